// Round 1
// baseline (119.195 us; speedup 1.0000x reference)
//
#include <hip/hip_runtime.h>
#include <math.h>

#define BIGV 10000000000.0f
#define WA   0.096f

// Distance fields D[vol][z][y][x], vol = b*3 + L, each 64^3 fp32.
// Labels y in {0,1,2}; field L is distance to voxels with y == L.

__global__ __launch_bounds__(256) void pass_z_kernel(const int* __restrict__ lab,
                                                     float* __restrict__ D) {
    const int vol = blockIdx.y;          // 0..5
    const int b   = vol / 3;
    const int L   = vol % 3;
    const int ys  = blockIdx.x;          // y index 0..63
    const int lane = threadIdx.x & 63;
    const int wv   = threadIdx.x >> 6;

    __shared__ float s[64][64];          // s[z][x]

    const int* lp = lab + b * 262144 + ys * 64;   // + z*4096 + x
    for (int z = wv; z < 64; z += 4)
        s[z][lane] = (lp[z * 4096 + lane] == L) ? 0.0f : BIGV;
    __syncthreads();

    const int ibase = wv * 16;
    float m[16];
#pragma unroll
    for (int ii = 0; ii < 16; ++ii) m[ii] = __builtin_inff();

    for (int j = 0; j < 64; ++j) {
        const float v  = s[j][lane];
        const float fb = (float)(ibase - j);
#pragma unroll
        for (int ii = 0; ii < 16; ++ii) {
            const float t = WA * (fb + (float)ii);   // == 0.096f * (i-j), exact int diff
            m[ii] = fminf(m[ii], __builtin_fmaf(t, t, v));
        }
    }

    float* Dp = D + vol * 262144 + ys * 64;          // + z*4096 + x
#pragma unroll
    for (int ii = 0; ii < 16; ++ii)
        Dp[(ibase + ii) * 4096 + lane] = m[ii];
}

__global__ __launch_bounds__(256) void pass_y_kernel(float* __restrict__ D) {
    const int vol = blockIdx.y;
    const int z   = blockIdx.x;
    const int lane = threadIdx.x & 63;
    const int wv   = threadIdx.x >> 6;

    __shared__ float s[64][64];          // s[y][x]
    float* Dp = D + (vol * 64 + z) * 4096;           // contiguous (y,x) slice
    float* sf = &s[0][0];
    for (int t = threadIdx.x; t < 4096; t += 256) sf[t] = Dp[t];
    __syncthreads();

    const int ibase = wv * 16;
    float m[16];
#pragma unroll
    for (int ii = 0; ii < 16; ++ii) m[ii] = __builtin_inff();

    for (int j = 0; j < 64; ++j) {
        const float v  = s[j][lane];
        const float fb = (float)(ibase - j);
#pragma unroll
        for (int ii = 0; ii < 16; ++ii) {
            const float t = WA * (fb + (float)ii);
            m[ii] = fminf(m[ii], __builtin_fmaf(t, t, v));
        }
    }

#pragma unroll
    for (int ii = 0; ii < 16; ++ii)
        Dp[(ibase + ii) * 64 + lane] = m[ii];
}

// One wave per (b,z,y) line. Finishes x-pass in registers via __shfl,
// combines with labels + x channels {1,2}, reduces to one partial per block.
__global__ __launch_bounds__(256) void pass_x_combine_kernel(const float* __restrict__ x,
                                                             const int* __restrict__ lab,
                                                             const float* __restrict__ D,
                                                             float* __restrict__ partials) {
    const int lane = threadIdx.x & 63;
    const int wv   = threadIdx.x >> 6;
    const int wid  = blockIdx.x * 4 + wv;  // 0..8191
    const int b  = wid >> 12;
    const int z  = (wid >> 6) & 63;
    const int yy = wid & 63;

    const int off = (z * 64 + yy) * 64 + lane;

    const float f0 = D[(b * 3 + 0) * 262144 + off];
    const float f1 = D[(b * 3 + 1) * 262144 + off];
    const float f2 = D[(b * 3 + 2) * 262144 + off];

    float m0 = __builtin_inff(), m1 = __builtin_inff(), m2 = __builtin_inff();
    for (int j = 0; j < 64; ++j) {
        const float t   = WA * (float)(lane - j);
        const float d2v = t * t;
        m0 = fminf(m0, __shfl(f0, j) + d2v);
        m1 = fminf(m1, __shfl(f1, j) + d2v);
        m2 = fminf(m2, __shfl(f2, j) + d2v);
    }

    const int lv = lab[b * 262144 + off];
    const float d0 = (lv == 0) ? BIGV : m0;
    const float d1 = (lv == 1) ? BIGV : m1;
    const float d2 = (lv == 2) ? BIGV : m2;
    const float dt = sqrtf(fminf(d0, fminf(d1, d2))) + 1.0f;

    const float x1 = x[(b * 3 + 1) * 262144 + off];
    const float x2 = x[(b * 3 + 2) * 262144 + off];
    const float t1 = (lv == 1) ? (1.0f - x1) : x1;
    const float t2 = (lv == 2) ? (1.0f - x2) : x2;
    float part = (t1 + t2) * dt;

#pragma unroll
    for (int o = 32; o; o >>= 1) part += __shfl_down(part, o);

    __shared__ float ps[4];
    if (lane == 0) ps[wv] = part;
    __syncthreads();
    if (threadIdx.x == 0)
        partials[blockIdx.x] = ps[0] + ps[1] + ps[2] + ps[3];
}

__global__ __launch_bounds__(256) void final_reduce_kernel(const float* __restrict__ partials,
                                                           float* __restrict__ out) {
    __shared__ float s[256];
    float v = 0.0f;
    for (int i = threadIdx.x; i < 2048; i += 256) v += partials[i];
    s[threadIdx.x] = v;
    __syncthreads();
    for (int st = 128; st > 0; st >>= 1) {
        if (threadIdx.x < st) s[threadIdx.x] += s[threadIdx.x + st];
        __syncthreads();
    }
    if (threadIdx.x == 0)
        out[0] = s[0] * (1.0f / 1048576.0f) + 1e-5f;
}

extern "C" void kernel_launch(void* const* d_in, const int* in_sizes, int n_in,
                              void* d_out, int out_size, void* d_ws, size_t ws_size,
                              hipStream_t stream) {
    const float* x  = (const float*)d_in[0];   // (2,3,64,64,64) fp32
    const int*   y  = (const int*)d_in[1];     // (2,1,64,64,64) int32
    float* D        = (float*)d_ws;            // 6 * 262144 floats = 6 MB
    float* partials = D + 6 * 262144;          // 2048 floats
    float* out      = (float*)d_out;

    pass_z_kernel<<<dim3(64, 6), 256, 0, stream>>>(y, D);
    pass_y_kernel<<<dim3(64, 6), 256, 0, stream>>>(D);
    pass_x_combine_kernel<<<dim3(2048), 256, 0, stream>>>(x, y, D, partials);
    final_reduce_kernel<<<dim3(1), 256, 0, stream>>>(partials, out);
}